// Round 8
// baseline (1139.739 us; speedup 1.0000x reference)
//
#include <hip/hip_runtime.h>
#include <math.h>

#define NU_    100000
#define NI_    50000
#define NB_    20000
#define DIM    64
#define E_UI_  2000000
#define E_BI_  600000
#define NPROP  (2 * E_UI_)
#define NTOT   (NU_ + NI_)
#define BATCH  4096
#define NBIN_P ((NTOT + 255) / 256)   // 586
#define NBIN_B ((NB_  + 255) / 256)   // 79

#define CAST_BLOCKS ((NTOT * 16 + 255) / 256)   // 9375
#define HISTP_BLOCKS 512
#define HISTB_BLOCKS 64
#define MSP_BLOCKS   768
#define MSB_BLOCKS   96

// ---------------------------------------------------------------------------
// bf16 helpers
__device__ __forceinline__ float bflo(unsigned int u) {
    return __uint_as_float(u << 16);
}
__device__ __forceinline__ float bfhi(unsigned int u) {
    return __uint_as_float(u & 0xFFFF0000u);
}
__device__ __forceinline__ unsigned short f2bf(float f) {         // RNE
    unsigned int u = __float_as_uint(f);
    u += 0x7FFFu + ((u >> 16) & 1u);
    return (unsigned short)(u >> 16);
}
__device__ __forceinline__ unsigned int pack2(float a, float b) {
    return (unsigned int)f2bf(a) | ((unsigned int)f2bf(b) << 16);
}

// ---------------------------------------------------------------------------
// Fused: bf16 cast (blocks [0,CAST)) + bin histogram P (next 512) + B (next 64)
__global__ void prep_kernel(const float4* __restrict__ uf4,
                            const float4* __restrict__ itf4,
                            uint2* __restrict__ feats_out,
                            const int* __restrict__ prows,
                            const int* __restrict__ brows,
                            int* __restrict__ bcntP,
                            int* __restrict__ bcntB) {
    __shared__ int lcnt[NBIN_P];
    int bid = blockIdx.x;
    if (bid < CAST_BLOCKS) {
        int i = bid * 256 + threadIdx.x;
        const int nuq = NU_ * 16;
        float4 v = (i < nuq) ? uf4[i] : itf4[i - nuq];
        uint2 o;
        o.x = pack2(v.x, v.y);
        o.y = pack2(v.z, v.w);
        feats_out[i] = o;
        return;
    }
    const int* rows; int n, nbin, vb, vgrid; int* bcnt;
    if (bid < CAST_BLOCKS + HISTP_BLOCKS) {
        rows = prows; n = NPROP; nbin = NBIN_P;
        vb = bid - CAST_BLOCKS; vgrid = HISTP_BLOCKS; bcnt = bcntP;
    } else {
        rows = brows; n = E_BI_; nbin = NBIN_B;
        vb = bid - CAST_BLOCKS - HISTP_BLOCKS; vgrid = HISTB_BLOCKS; bcnt = bcntB;
    }
    for (int i = threadIdx.x; i < nbin; i += 256) lcnt[i] = 0;
    __syncthreads();
    int stride = vgrid * 256 * 4;
    for (int base = vb * 256 * 4; base < n; base += stride) {
        #pragma unroll
        for (int j = 0; j < 4; ++j) {
            int i = base + j * 256 + threadIdx.x;
            if (i < n) atomicAdd(&lcnt[rows[i] >> 8], 1);
        }
    }
    __syncthreads();
    for (int i = threadIdx.x; i < nbin; i += 256)
        if (lcnt[i] > 0) atomicAdd(&bcnt[i], lcnt[i]);
}

// ---------------------------------------------------------------------------
// Exclusive scan of bcnt -> binoff, gcur. Block 0: P, block 1: B.
__global__ void scan_kernel(const int* __restrict__ bcntP, int* __restrict__ binoffP,
                            int* __restrict__ gcurP,
                            const int* __restrict__ bcntB, int* __restrict__ binoffB,
                            int* __restrict__ gcurB) {
    __shared__ int tmp[1024];
    const int* bcnt; int* binoff; int* gcur; int nbin;
    if (blockIdx.x == 0) { bcnt = bcntP; binoff = binoffP; gcur = gcurP; nbin = NBIN_P; }
    else                 { bcnt = bcntB; binoff = binoffB; gcur = gcurB; nbin = NBIN_B; }
    int t = threadIdx.x;
    int x = (t < nbin) ? bcnt[t] : 0;
    tmp[t] = x;
    __syncthreads();
    for (int o = 1; o < 1024; o <<= 1) {
        int y = (t >= o) ? tmp[t - o] : 0;
        __syncthreads();
        tmp[t] += y;
        __syncthreads();
    }
    if (t < nbin) {
        int v = tmp[t] - x;
        binoff[t] = v;
        gcur[t]   = v;
    }
}

// ---------------------------------------------------------------------------
// Fused LDS-staged multisplit (P: blocks [0,768), B: [768,864)).
// 8 edges/thread per barrier cycle; wave-parallel drain.
// payload = ((row & 255) << 24) | col
__global__ void multisplit_kernel(const int* __restrict__ prows,
                                  const int* __restrict__ pcols,
                                  const int* __restrict__ brows,
                                  const int* __restrict__ bcols,
                                  int* __restrict__ gcurP,
                                  unsigned int* __restrict__ binnedP,
                                  int* __restrict__ gcurB,
                                  unsigned int* __restrict__ binnedB) {
    constexpr int BUF = 16;
    __shared__ int cnt[NBIN_P];
    __shared__ int basep[NBIN_P];
    __shared__ unsigned int stage[NBIN_P][BUF];
    const int *rows, *cols; int n, nbin, vb, vgrid;
    int* gcur; unsigned int* binned;
    if (blockIdx.x < MSP_BLOCKS) {
        rows = prows; cols = pcols; n = NPROP; nbin = NBIN_P;
        vb = blockIdx.x; vgrid = MSP_BLOCKS; gcur = gcurP; binned = binnedP;
    } else {
        rows = brows; cols = bcols; n = E_BI_; nbin = NBIN_B;
        vb = blockIdx.x - MSP_BLOCKS; vgrid = MSB_BLOCKS; gcur = gcurB; binned = binnedB;
    }
    for (int i = threadIdx.x; i < nbin; i += 256) cnt[i] = 0;
    __syncthreads();
    int stride = vgrid * 256 * 8;
    for (int base = vb * 256 * 8; base < n; base += stride) {
        int bin[8], pos[8];
        unsigned int payload[8];
        #pragma unroll
        for (int j = 0; j < 8; ++j) {
            int i = base + j * 256 + threadIdx.x;   // coalesced per step
            pos[j] = -1;
            if (i < n) {
                int r = rows[i];
                int c = cols[i];
                bin[j] = r >> 8;
                payload[j] = ((unsigned int)(r & 255) << 24) | (unsigned int)c;
                pos[j] = atomicAdd(&cnt[bin[j]], 1);
                if (pos[j] < BUF) stage[bin[j]][pos[j]] = payload[j];
            }
        }
        __syncthreads();
        #pragma unroll
        for (int j = 0; j < 8; ++j)
            if (pos[j] == BUF)                 // unique leader per bin
                basep[bin[j]] = atomicAdd(&gcur[bin[j]], cnt[bin[j]]);
        __syncthreads();
        #pragma unroll
        for (int j = 0; j < 8; ++j) {
            if (pos[j] >= BUF) {
                binned[basep[bin[j]] + pos[j]] = payload[j];
                if (pos[j] == BUF) {
                    int b0 = basep[bin[j]];
                    #pragma unroll
                    for (int q = 0; q < BUF; ++q) binned[b0 + q] = stage[bin[j]][q];
                    cnt[bin[j]] = 0;
                }
            }
        }
        __syncthreads();
    }
    // wave-parallel drain: lane j writes staged entry j of the wave's bin
    int wv = threadIdx.x >> 6;
    int ln = threadIdx.x & 63;
    for (int b = wv; b < nbin; b += 4) {
        int c = cnt[b];
        if (c > 0) {
            int b0 = 0;
            if (ln == 0) b0 = atomicAdd(&gcur[b], c);
            b0 = __shfl(b0, 0, 64);
            if (ln < c) binned[b0 + ln] = stage[b][ln];
        }
    }
}

// ---------------------------------------------------------------------------
// Fused per-bin CSR build (P: blocks [0,586), B: [586,665)).
__global__ void bin_csr_kernel(const unsigned int* __restrict__ binnedP,
                               const int* __restrict__ binoffP,
                               int* __restrict__ offP, int* __restrict__ degP,
                               float* __restrict__ invsP, int* __restrict__ cvP,
                               const unsigned int* __restrict__ binnedB,
                               const int* __restrict__ binoffB,
                               int* __restrict__ offB, int* __restrict__ degB,
                               int* __restrict__ cvB) {
    __shared__ int cnt[256];
    __shared__ int cur[256];
    __shared__ int scanbuf[256];
    const unsigned int* binned; const int* binoff;
    int* off; int* deg; float* invs; int* cv;
    int b, nbin, n, nrows;
    if (blockIdx.x < NBIN_P) {
        b = blockIdx.x; binned = binnedP; binoff = binoffP; n = NPROP;
        nbin = NBIN_P; nrows = NTOT;
        off = offP; deg = degP; invs = invsP; cv = cvP;
    } else {
        b = blockIdx.x - NBIN_P; binned = binnedB; binoff = binoffB; n = E_BI_;
        nbin = NBIN_B; nrows = NB_;
        off = offB; deg = degB; invs = (float*)0; cv = cvB;
    }
    int t = threadIdx.x;
    int rowbase = b << 8;
    cnt[t] = 0;
    __syncthreads();
    int s = binoff[b];
    int e = (b + 1 < nbin) ? binoff[b + 1] : n;
    for (int i = s + t; i < e; i += 256)
        atomicAdd(&cnt[binned[i] >> 24], 1);
    __syncthreads();
    int x = cnt[t];
    scanbuf[t] = x;
    __syncthreads();
    for (int o = 1; o < 256; o <<= 1) {
        int y = (t >= o) ? scanbuf[t - o] : 0;
        __syncthreads();
        scanbuf[t] += y;
        __syncthreads();
    }
    int base = s + scanbuf[t] - x;
    cur[t] = base;
    if (rowbase + t < nrows) {
        off[rowbase + t] = base;
        deg[rowbase + t] = x;
        if (invs) invs[rowbase + t] = 1.0f / (sqrtf((float)x) + 1e-8f);
    }
    __syncthreads();
    for (int i = s + t; i < e; i += 256) {
        unsigned int p = binned[i];
        int slot = atomicAdd(&cur[p >> 24], 1);
        cv[slot] = (int)(p & 0xFFFFFFu);
    }
}

// ---------------------------------------------------------------------------
// 8 lanes/row, uint4 = 8 bf16 per lane. 8 rows/wave, 32 rows per 256-block.
__device__ __forceinline__ void fma8(float* s, float v, uint4 x) {
    s[0] = fmaf(v, bflo(x.x), s[0]);
    s[1] = fmaf(v, bfhi(x.x), s[1]);
    s[2] = fmaf(v, bflo(x.y), s[2]);
    s[3] = fmaf(v, bfhi(x.y), s[3]);
    s[4] = fmaf(v, bflo(x.z), s[4]);
    s[5] = fmaf(v, bfhi(x.z), s[5]);
    s[6] = fmaf(v, bflo(x.w), s[6]);
    s[7] = fmaf(v, bfhi(x.w), s[7]);
}
__device__ __forceinline__ uint4 pack8(const float* s) {
    uint4 o;
    o.x = pack2(s[0], s[1]);
    o.y = pack2(s[2], s[3]);
    o.z = pack2(s[4], s[5]);
    o.w = pack2(s[6], s[7]);
    return o;
}

// Layer 1: sum = Σ invs[c]·feats[c]; acc16[r] = feats[r] + invs[r]·sum;
//          f1s16[r] = invs[r]²·sum
__global__ void layer1_kernel(const int* __restrict__ off,
                              const int* __restrict__ deg,
                              const int* __restrict__ cv,
                              const float* __restrict__ invs,
                              const uint4* __restrict__ feats16,
                              uint4* __restrict__ f1s16,
                              uint4* __restrict__ acc16) {
    int wave = blockIdx.x * (blockDim.x >> 6) + (threadIdx.x >> 6);
    int sub  = (threadIdx.x >> 3) & 7;
    int l    = threadIdx.x & 7;
    int row  = wave * 8 + sub;
    if (row >= NTOT) return;
    int s = off[row], d = deg[row];
    float sum[8] = {0.f, 0.f, 0.f, 0.f, 0.f, 0.f, 0.f, 0.f};
    int k = 0;
    for (; k + 4 <= d; k += 4) {
        int c0 = cv[s + k + 0];
        int c1 = cv[s + k + 1];
        int c2 = cv[s + k + 2];
        int c3 = cv[s + k + 3];
        float w0 = invs[c0], w1 = invs[c1], w2 = invs[c2], w3 = invs[c3];
        uint4 x0 = feats16[(size_t)c0 * 8 + l];
        uint4 x1 = feats16[(size_t)c1 * 8 + l];
        uint4 x2 = feats16[(size_t)c2 * 8 + l];
        uint4 x3 = feats16[(size_t)c3 * 8 + l];
        fma8(sum, w0, x0);
        fma8(sum, w1, x1);
        fma8(sum, w2, x2);
        fma8(sum, w3, x3);
    }
    for (; k < d; ++k) {
        int c = cv[s + k];
        uint4 x = feats16[(size_t)c * 8 + l];
        fma8(sum, invs[c], x);
    }
    float ivr = invs[row];
    uint4 bx = feats16[(size_t)row * 8 + l];
    float base[8] = {bflo(bx.x), bfhi(bx.x), bflo(bx.y), bfhi(bx.y),
                     bflo(bx.z), bfhi(bx.z), bflo(bx.w), bfhi(bx.w)};
    float a[8], fs[8];
    float iv2 = ivr * ivr;
    #pragma unroll
    for (int j = 0; j < 8; ++j) {
        a[j]  = fmaf(ivr, sum[j], base[j]);
        fs[j] = iv2 * sum[j];
    }
    size_t idx = (size_t)row * 8 + l;
    acc16[idx] = pack8(a);
    f1s16[idx] = pack8(fs);
}

// Layer 2: acc16[r] += invs[r] * Σ f1s16[c]
__global__ void layer2_kernel(const int* __restrict__ off,
                              const int* __restrict__ deg,
                              const int* __restrict__ cv,
                              const float* __restrict__ invs,
                              const uint4* __restrict__ f1s16,
                              uint4* __restrict__ acc16) {
    int wave = blockIdx.x * (blockDim.x >> 6) + (threadIdx.x >> 6);
    int sub  = (threadIdx.x >> 3) & 7;
    int l    = threadIdx.x & 7;
    int row  = wave * 8 + sub;
    if (row >= NTOT) return;
    int s = off[row], d = deg[row];
    float sum[8] = {0.f, 0.f, 0.f, 0.f, 0.f, 0.f, 0.f, 0.f};
    int k = 0;
    for (; k + 4 <= d; k += 4) {
        int c0 = cv[s + k + 0];
        int c1 = cv[s + k + 1];
        int c2 = cv[s + k + 2];
        int c3 = cv[s + k + 3];
        uint4 x0 = f1s16[(size_t)c0 * 8 + l];
        uint4 x1 = f1s16[(size_t)c1 * 8 + l];
        uint4 x2 = f1s16[(size_t)c2 * 8 + l];
        uint4 x3 = f1s16[(size_t)c3 * 8 + l];
        fma8(sum, 1.f, x0);
        fma8(sum, 1.f, x1);
        fma8(sum, 1.f, x2);
        fma8(sum, 1.f, x3);
    }
    for (; k < d; ++k) {
        int c = cv[s + k];
        uint4 x = f1s16[(size_t)c * 8 + l];
        fma8(sum, 1.f, x);
    }
    float ivr = invs[row];
    size_t idx = (size_t)row * 8 + l;
    uint4 ax = acc16[idx];
    float a[8] = {bflo(ax.x), bfhi(ax.x), bflo(ax.y), bfhi(ax.y),
                  bflo(ax.z), bfhi(ax.z), bflo(ax.w), bfhi(ax.w)};
    #pragma unroll
    for (int j = 0; j < 8; ++j) a[j] = fmaf(ivr, sum[j], a[j]);
    acc16[idx] = pack8(a);
}

// Bundle SpMM: brep[r] = (1/3)/(deg+1e-8) * Σ acc16[NU+c]   (fp32 out)
__global__ void bi_csr_kernel(const int* __restrict__ off,
                              const int* __restrict__ deg,
                              const int* __restrict__ cv,
                              const uint4* __restrict__ acc16,
                              float* __restrict__ brep) {
    int wave = blockIdx.x * (blockDim.x >> 6) + (threadIdx.x >> 6);
    int sub  = (threadIdx.x >> 3) & 7;
    int l    = threadIdx.x & 7;
    int row  = wave * 8 + sub;
    if (row >= NB_) return;
    int s = off[row], d = deg[row];
    float sum[8] = {0.f, 0.f, 0.f, 0.f, 0.f, 0.f, 0.f, 0.f};
    int k = 0;
    for (; k + 4 <= d; k += 4) {
        int c0 = cv[s + k + 0];
        int c1 = cv[s + k + 1];
        int c2 = cv[s + k + 2];
        int c3 = cv[s + k + 3];
        uint4 x0 = acc16[(size_t)(NU_ + c0) * 8 + l];
        uint4 x1 = acc16[(size_t)(NU_ + c1) * 8 + l];
        uint4 x2 = acc16[(size_t)(NU_ + c2) * 8 + l];
        uint4 x3 = acc16[(size_t)(NU_ + c3) * 8 + l];
        fma8(sum, 1.f, x0);
        fma8(sum, 1.f, x1);
        fma8(sum, 1.f, x2);
        fma8(sum, 1.f, x3);
    }
    for (; k < d; ++k) {
        int c = cv[s + k];
        uint4 x = acc16[(size_t)(NU_ + c) * 8 + l];
        fma8(sum, 1.f, x);
    }
    float scale = (1.0f / 3.0f) / ((float)d + 1e-8f);
    float4 o0, o1;
    o0.x = sum[0] * scale; o0.y = sum[1] * scale;
    o0.z = sum[2] * scale; o0.w = sum[3] * scale;
    o1.x = sum[4] * scale; o1.y = sum[5] * scale;
    o1.z = sum[6] * scale; o1.w = sum[7] * scale;
    float4* bp = (float4*)(brep + (size_t)row * DIM + l * 8);
    bp[0] = o0;
    bp[1] = o1;
}

// ---------------------------------------------------------------------------
__global__ void score_kernel(const unsigned short* __restrict__ acc16u,
                             const float* __restrict__ brep,
                             const int*   __restrict__ users,
                             const int*   __restrict__ bundles,
                             float* __restrict__ loss_sum) {
    int tid  = blockIdx.x * blockDim.x + threadIdx.x;
    int b    = tid >> 6;
    int lane = tid & 63;
    if (b >= BATCH) return;
    int u  = users[b];
    int b0 = bundles[2 * b];
    int b1 = bundles[2 * b + 1];
    float du = __uint_as_float((unsigned int)acc16u[(size_t)u * DIM + lane] << 16)
               * (1.0f / 3.0f);
    float d  = du * (brep[(size_t)b0 * DIM + lane] -
                     brep[(size_t)b1 * DIM + lane]);
    #pragma unroll
    for (int off = 32; off > 0; off >>= 1)
        d += __shfl_down(d, off, 64);
    if (lane == 0) {
        float x = d;
        float l = fmaxf(-x, 0.0f) + log1pf(expf(-fabsf(x)));
        atomicAdd(loss_sum, l);
    }
}

// ---------------------------------------------------------------------------
__global__ void finalize_kernel(const float* __restrict__ loss_sum,
                                float* __restrict__ out) {
    out[0] = loss_sum[0] * (1.0f / BATCH);
    out[1] = 0.0f;
}

// ---------------------------------------------------------------------------
extern "C" void kernel_launch(void* const* d_in, const int* in_sizes, int n_in,
                              void* d_out, int out_size, void* d_ws, size_t ws_size,
                              hipStream_t stream) {
    const float* uf        = (const float*)d_in[0];
    const float* itf       = (const float*)d_in[1];
    const int*   prop_rows = (const int*)  d_in[4];
    const int*   prop_cols = (const int*)  d_in[5];
    const int*   bi_rows   = (const int*)  d_in[6];
    const int*   bi_cols   = (const int*)  d_in[7];
    const int*   users     = (const int*)  d_in[8];
    const int*   bundles   = (const int*)  d_in[9];
    float* out = (float*)d_out;

    char* ws = (char*)d_ws;
    uint4*        acc16   = (uint4*)       (ws + 0);           // 19.2 MB
    uint4*        f1s16   = (uint4*)       (ws + 19200000);    // 19.2 MB
    uint4*        feats16 = (uint4*)       (ws + 38400000);    // 19.2 MB
    float*        brep    = (float*)       (ws + 57600000);    // 5.12 MB
    int*          cvP     = (int*)         (ws + 62720000);    // 16 MB
    unsigned int* binnedP = (unsigned int*)(ws + 78720000);    // 16 MB
    int*          cvB     = (int*)         (ws + 94720000);    // 2.4 MB
    unsigned int* binnedB = (unsigned int*)(ws + 97120000);    // 2.4 MB
    int*          degP    = (int*)         (ws + 99520000);
    int*          offP    = (int*)         (ws + 100120000);
    float*        invsP   = (float*)       (ws + 100720000);
    int*          degB    = (int*)         (ws + 101320000);
    int*          offB    = (int*)         (ws + 101400000);
    int*          binoffP = (int*)         (ws + 101480000);
    int*          gcurP   = (int*)         (ws + 101482368);
    int*          binoffB = (int*)         (ws + 101484736);
    int*          gcurB   = (int*)         (ws + 101485056);
    // contiguous zero-init region: bcntP | bcntB | loss
    int*          bcntP   = (int*)         (ws + 101485376);   // 2368 B
    int*          bcntB   = (int*)         (ws + 101487744);   // 320 B
    float*        loss    = (float*)       (ws + 101488064);   // 4 B

    hipMemsetAsync(bcntP, 0, 2692, stream);   // bcntP + bcntB + loss

    // 1) cast + histograms (fused)
    prep_kernel<<<CAST_BLOCKS + HISTP_BLOCKS + HISTB_BLOCKS, 256, 0, stream>>>(
        (const float4*)uf, (const float4*)itf, (uint2*)feats16,
        prop_rows, bi_rows, bcntP, bcntB);

    // 2) bin-offset scans (P and B in one launch)
    scan_kernel<<<2, 1024, 0, stream>>>(bcntP, binoffP, gcurP,
                                        bcntB, binoffB, gcurB);

    // 3) staged multisplit (P+B fused)
    multisplit_kernel<<<MSP_BLOCKS + MSB_BLOCKS, 256, 0, stream>>>(
        prop_rows, prop_cols, bi_rows, bi_cols,
        gcurP, binnedP, gcurB, binnedB);

    // 4) per-bin CSR build (P+B fused)
    bin_csr_kernel<<<NBIN_P + NBIN_B, 256, 0, stream>>>(
        binnedP, binoffP, offP, degP, invsP, cvP,
        binnedB, binoffB, offB, degB, cvB);

    // 5-7) propagation
    layer1_kernel<<<(NTOT + 31) / 32, 256, 0, stream>>>(offP, degP, cvP, invsP,
                                                        feats16, f1s16, acc16);
    layer2_kernel<<<(NTOT + 31) / 32, 256, 0, stream>>>(offP, degP, cvP, invsP,
                                                        f1s16, acc16);
    bi_csr_kernel<<<(NB_ + 31) / 32, 256, 0, stream>>>(offB, degB, cvB, acc16, brep);

    // 8-9) loss
    score_kernel<<<BATCH * 64 / 256, 256, 0, stream>>>(
        (const unsigned short*)acc16, brep, users, bundles, loss);
    finalize_kernel<<<1, 1, 0, stream>>>(loss, out);
}

// Round 9
// 506.620 us; speedup vs baseline: 2.2497x; 2.2497x over previous
//
#include <hip/hip_runtime.h>
#include <math.h>

#define NU_    100000
#define NI_    50000
#define NB_    20000
#define DIM    64
#define E_UI_  2000000
#define E_BI_  600000
#define NPROP  (2 * E_UI_)
#define NTOT   (NU_ + NI_)
#define BATCH  4096
#define NBIN_P ((NTOT + 255) / 256)   // 586
#define NBIN_B ((NB_  + 255) / 256)   // 79

#define CAST_BLOCKS ((NTOT * 16 + 255) / 256)   // 9375
#define HISTP_BLOCKS 512
#define HISTB_BLOCKS 64
#define MSP_BLOCKS   768
#define MSB_BLOCKS   96

// ---------------------------------------------------------------------------
// bf16 helpers
__device__ __forceinline__ float bflo(unsigned int u) {
    return __uint_as_float(u << 16);
}
__device__ __forceinline__ float bfhi(unsigned int u) {
    return __uint_as_float(u & 0xFFFF0000u);
}
__device__ __forceinline__ unsigned short f2bf(float f) {         // RNE
    unsigned int u = __float_as_uint(f);
    u += 0x7FFFu + ((u >> 16) & 1u);
    return (unsigned short)(u >> 16);
}
__device__ __forceinline__ unsigned int pack2(float a, float b) {
    return (unsigned int)f2bf(a) | ((unsigned int)f2bf(b) << 16);
}

// ---------------------------------------------------------------------------
// Fused: bf16 cast (blocks [0,CAST)) + bin histogram P (next 512) + B (next 64)
__global__ void prep_kernel(const float4* __restrict__ uf4,
                            const float4* __restrict__ itf4,
                            uint2* __restrict__ feats_out,
                            const int* __restrict__ prows,
                            const int* __restrict__ brows,
                            int* __restrict__ bcntP,
                            int* __restrict__ bcntB) {
    __shared__ int lcnt[NBIN_P];
    int bid = blockIdx.x;
    if (bid < CAST_BLOCKS) {
        int i = bid * 256 + threadIdx.x;
        const int nuq = NU_ * 16;
        float4 v = (i < nuq) ? uf4[i] : itf4[i - nuq];
        uint2 o;
        o.x = pack2(v.x, v.y);
        o.y = pack2(v.z, v.w);
        feats_out[i] = o;
        return;
    }
    const int* rows; int n, nbin, vb, vgrid; int* bcnt;
    if (bid < CAST_BLOCKS + HISTP_BLOCKS) {
        rows = prows; n = NPROP; nbin = NBIN_P;
        vb = bid - CAST_BLOCKS; vgrid = HISTP_BLOCKS; bcnt = bcntP;
    } else {
        rows = brows; n = E_BI_; nbin = NBIN_B;
        vb = bid - CAST_BLOCKS - HISTP_BLOCKS; vgrid = HISTB_BLOCKS; bcnt = bcntB;
    }
    for (int i = threadIdx.x; i < nbin; i += 256) lcnt[i] = 0;
    __syncthreads();
    int stride = vgrid * 256 * 4;
    for (int base = vb * 256 * 4; base < n; base += stride) {
        #pragma unroll
        for (int j = 0; j < 4; ++j) {
            int i = base + j * 256 + threadIdx.x;
            if (i < n) atomicAdd(&lcnt[rows[i] >> 8], 1);
        }
    }
    __syncthreads();
    for (int i = threadIdx.x; i < nbin; i += 256)
        if (lcnt[i] > 0) atomicAdd(&bcnt[i], lcnt[i]);
}

// ---------------------------------------------------------------------------
// Exclusive scan of bcnt -> binoff, gcur. Block 0: P, block 1: B.
__global__ void scan_kernel(const int* __restrict__ bcntP, int* __restrict__ binoffP,
                            int* __restrict__ gcurP,
                            const int* __restrict__ bcntB, int* __restrict__ binoffB,
                            int* __restrict__ gcurB) {
    __shared__ int tmp[1024];
    const int* bcnt; int* binoff; int* gcur; int nbin;
    if (blockIdx.x == 0) { bcnt = bcntP; binoff = binoffP; gcur = gcurP; nbin = NBIN_P; }
    else                 { bcnt = bcntB; binoff = binoffB; gcur = gcurB; nbin = NBIN_B; }
    int t = threadIdx.x;
    int x = (t < nbin) ? bcnt[t] : 0;
    tmp[t] = x;
    __syncthreads();
    for (int o = 1; o < 1024; o <<= 1) {
        int y = (t >= o) ? tmp[t - o] : 0;
        __syncthreads();
        tmp[t] += y;
        __syncthreads();
    }
    if (t < nbin) {
        int v = tmp[t] - x;
        binoff[t] = v;
        gcur[t]   = v;
    }
}

// ---------------------------------------------------------------------------
// Fused LDS-staged multisplit (P: blocks [0,768), B: [768,864)).
// 8 edges/thread per barrier cycle; per-thread drain (256 concurrent chains).
// payload = ((row & 255) << 24) | col
__global__ void multisplit_kernel(const int* __restrict__ prows,
                                  const int* __restrict__ pcols,
                                  const int* __restrict__ brows,
                                  const int* __restrict__ bcols,
                                  int* __restrict__ gcurP,
                                  unsigned int* __restrict__ binnedP,
                                  int* __restrict__ gcurB,
                                  unsigned int* __restrict__ binnedB) {
    constexpr int BUF = 16;
    __shared__ int cnt[NBIN_P];
    __shared__ int basep[NBIN_P];
    __shared__ unsigned int stage[NBIN_P][BUF];
    const int *rows, *cols; int n, nbin, vb, vgrid;
    int* gcur; unsigned int* binned;
    if (blockIdx.x < MSP_BLOCKS) {
        rows = prows; cols = pcols; n = NPROP; nbin = NBIN_P;
        vb = blockIdx.x; vgrid = MSP_BLOCKS; gcur = gcurP; binned = binnedP;
    } else {
        rows = brows; cols = bcols; n = E_BI_; nbin = NBIN_B;
        vb = blockIdx.x - MSP_BLOCKS; vgrid = MSB_BLOCKS; gcur = gcurB; binned = binnedB;
    }
    for (int i = threadIdx.x; i < nbin; i += 256) cnt[i] = 0;
    __syncthreads();
    int stride = vgrid * 256 * 8;
    for (int base = vb * 256 * 8; base < n; base += stride) {
        int bin[8], pos[8];
        unsigned int payload[8];
        #pragma unroll
        for (int j = 0; j < 8; ++j) {
            int i = base + j * 256 + threadIdx.x;   // coalesced per step
            pos[j] = -1;
            if (i < n) {
                int r = rows[i];
                int c = cols[i];
                bin[j] = r >> 8;
                payload[j] = ((unsigned int)(r & 255) << 24) | (unsigned int)c;
                pos[j] = atomicAdd(&cnt[bin[j]], 1);
                if (pos[j] < BUF) stage[bin[j]][pos[j]] = payload[j];
            }
        }
        __syncthreads();
        #pragma unroll
        for (int j = 0; j < 8; ++j)
            if (pos[j] == BUF)                 // unique leader per bin
                basep[bin[j]] = atomicAdd(&gcur[bin[j]], cnt[bin[j]]);
        __syncthreads();
        #pragma unroll
        for (int j = 0; j < 8; ++j) {
            if (pos[j] >= BUF) {
                binned[basep[bin[j]] + pos[j]] = payload[j];
                if (pos[j] == BUF) {
                    int b0 = basep[bin[j]];
                    #pragma unroll
                    for (int q = 0; q < BUF; ++q) binned[b0 + q] = stage[bin[j]][q];
                    cnt[bin[j]] = 0;
                }
            }
        }
        __syncthreads();
    }
    // per-thread drain: 256 independent atomic+store chains (R7 layout)
    for (int b = threadIdx.x; b < nbin; b += 256) {
        int c = cnt[b];
        if (c > 0) {
            int b0 = atomicAdd(&gcur[b], c);
            for (int j = 0; j < c; ++j) binned[b0 + j] = stage[b][j];
        }
    }
}

// ---------------------------------------------------------------------------
// Fused per-bin CSR build (P: blocks [0,586), B: [586,665)).
__global__ void bin_csr_kernel(const unsigned int* __restrict__ binnedP,
                               const int* __restrict__ binoffP,
                               int* __restrict__ offP, int* __restrict__ degP,
                               float* __restrict__ invsP, int* __restrict__ cvP,
                               const unsigned int* __restrict__ binnedB,
                               const int* __restrict__ binoffB,
                               int* __restrict__ offB, int* __restrict__ degB,
                               int* __restrict__ cvB) {
    __shared__ int cnt[256];
    __shared__ int cur[256];
    __shared__ int scanbuf[256];
    const unsigned int* binned; const int* binoff;
    int* off; int* deg; float* invs; int* cv;
    int b, nbin, n, nrows;
    if (blockIdx.x < NBIN_P) {
        b = blockIdx.x; binned = binnedP; binoff = binoffP; n = NPROP;
        nbin = NBIN_P; nrows = NTOT;
        off = offP; deg = degP; invs = invsP; cv = cvP;
    } else {
        b = blockIdx.x - NBIN_P; binned = binnedB; binoff = binoffB; n = E_BI_;
        nbin = NBIN_B; nrows = NB_;
        off = offB; deg = degB; invs = (float*)0; cv = cvB;
    }
    int t = threadIdx.x;
    int rowbase = b << 8;
    cnt[t] = 0;
    __syncthreads();
    int s = binoff[b];
    int e = (b + 1 < nbin) ? binoff[b + 1] : n;
    for (int i = s + t; i < e; i += 256)
        atomicAdd(&cnt[binned[i] >> 24], 1);
    __syncthreads();
    int x = cnt[t];
    scanbuf[t] = x;
    __syncthreads();
    for (int o = 1; o < 256; o <<= 1) {
        int y = (t >= o) ? scanbuf[t - o] : 0;
        __syncthreads();
        scanbuf[t] += y;
        __syncthreads();
    }
    int base = s + scanbuf[t] - x;
    cur[t] = base;
    if (rowbase + t < nrows) {
        off[rowbase + t] = base;
        deg[rowbase + t] = x;
        if (invs) invs[rowbase + t] = 1.0f / (sqrtf((float)x) + 1e-8f);
    }
    __syncthreads();
    for (int i = s + t; i < e; i += 256) {
        unsigned int p = binned[i];
        int slot = atomicAdd(&cur[p >> 24], 1);
        cv[slot] = (int)(p & 0xFFFFFFu);
    }
}

// ---------------------------------------------------------------------------
// 8 lanes/row, uint4 = 8 bf16 per lane. 8 rows/wave, 32 rows per 256-block.
__device__ __forceinline__ void fma8(float* s, float v, uint4 x) {
    s[0] = fmaf(v, bflo(x.x), s[0]);
    s[1] = fmaf(v, bfhi(x.x), s[1]);
    s[2] = fmaf(v, bflo(x.y), s[2]);
    s[3] = fmaf(v, bfhi(x.y), s[3]);
    s[4] = fmaf(v, bflo(x.z), s[4]);
    s[5] = fmaf(v, bfhi(x.z), s[5]);
    s[6] = fmaf(v, bflo(x.w), s[6]);
    s[7] = fmaf(v, bfhi(x.w), s[7]);
}
__device__ __forceinline__ uint4 pack8(const float* s) {
    uint4 o;
    o.x = pack2(s[0], s[1]);
    o.y = pack2(s[2], s[3]);
    o.z = pack2(s[4], s[5]);
    o.w = pack2(s[6], s[7]);
    return o;
}

// Layer 1: sum = Σ invs[c]·feats[c]; acc16[r] = feats[r] + invs[r]·sum;
//          f1s16[r] = invs[r]²·sum
__global__ void layer1_kernel(const int* __restrict__ off,
                              const int* __restrict__ deg,
                              const int* __restrict__ cv,
                              const float* __restrict__ invs,
                              const uint4* __restrict__ feats16,
                              uint4* __restrict__ f1s16,
                              uint4* __restrict__ acc16) {
    int wave = blockIdx.x * (blockDim.x >> 6) + (threadIdx.x >> 6);
    int sub  = (threadIdx.x >> 3) & 7;
    int l    = threadIdx.x & 7;
    int row  = wave * 8 + sub;
    if (row >= NTOT) return;
    int s = off[row], d = deg[row];
    float sum[8] = {0.f, 0.f, 0.f, 0.f, 0.f, 0.f, 0.f, 0.f};
    int k = 0;
    for (; k + 4 <= d; k += 4) {
        int c0 = cv[s + k + 0];
        int c1 = cv[s + k + 1];
        int c2 = cv[s + k + 2];
        int c3 = cv[s + k + 3];
        float w0 = invs[c0], w1 = invs[c1], w2 = invs[c2], w3 = invs[c3];
        uint4 x0 = feats16[(size_t)c0 * 8 + l];
        uint4 x1 = feats16[(size_t)c1 * 8 + l];
        uint4 x2 = feats16[(size_t)c2 * 8 + l];
        uint4 x3 = feats16[(size_t)c3 * 8 + l];
        fma8(sum, w0, x0);
        fma8(sum, w1, x1);
        fma8(sum, w2, x2);
        fma8(sum, w3, x3);
    }
    for (; k < d; ++k) {
        int c = cv[s + k];
        uint4 x = feats16[(size_t)c * 8 + l];
        fma8(sum, invs[c], x);
    }
    float ivr = invs[row];
    uint4 bx = feats16[(size_t)row * 8 + l];
    float base[8] = {bflo(bx.x), bfhi(bx.x), bflo(bx.y), bfhi(bx.y),
                     bflo(bx.z), bfhi(bx.z), bflo(bx.w), bfhi(bx.w)};
    float a[8], fs[8];
    float iv2 = ivr * ivr;
    #pragma unroll
    for (int j = 0; j < 8; ++j) {
        a[j]  = fmaf(ivr, sum[j], base[j]);
        fs[j] = iv2 * sum[j];
    }
    size_t idx = (size_t)row * 8 + l;
    acc16[idx] = pack8(a);
    f1s16[idx] = pack8(fs);
}

// Layer 2: acc16[r] += invs[r] * Σ f1s16[c]
__global__ void layer2_kernel(const int* __restrict__ off,
                              const int* __restrict__ deg,
                              const int* __restrict__ cv,
                              const float* __restrict__ invs,
                              const uint4* __restrict__ f1s16,
                              uint4* __restrict__ acc16) {
    int wave = blockIdx.x * (blockDim.x >> 6) + (threadIdx.x >> 6);
    int sub  = (threadIdx.x >> 3) & 7;
    int l    = threadIdx.x & 7;
    int row  = wave * 8 + sub;
    if (row >= NTOT) return;
    int s = off[row], d = deg[row];
    float sum[8] = {0.f, 0.f, 0.f, 0.f, 0.f, 0.f, 0.f, 0.f};
    int k = 0;
    for (; k + 4 <= d; k += 4) {
        int c0 = cv[s + k + 0];
        int c1 = cv[s + k + 1];
        int c2 = cv[s + k + 2];
        int c3 = cv[s + k + 3];
        uint4 x0 = f1s16[(size_t)c0 * 8 + l];
        uint4 x1 = f1s16[(size_t)c1 * 8 + l];
        uint4 x2 = f1s16[(size_t)c2 * 8 + l];
        uint4 x3 = f1s16[(size_t)c3 * 8 + l];
        fma8(sum, 1.f, x0);
        fma8(sum, 1.f, x1);
        fma8(sum, 1.f, x2);
        fma8(sum, 1.f, x3);
    }
    for (; k < d; ++k) {
        int c = cv[s + k];
        uint4 x = f1s16[(size_t)c * 8 + l];
        fma8(sum, 1.f, x);
    }
    float ivr = invs[row];
    size_t idx = (size_t)row * 8 + l;
    uint4 ax = acc16[idx];
    float a[8] = {bflo(ax.x), bfhi(ax.x), bflo(ax.y), bfhi(ax.y),
                  bflo(ax.z), bfhi(ax.z), bflo(ax.w), bfhi(ax.w)};
    #pragma unroll
    for (int j = 0; j < 8; ++j) a[j] = fmaf(ivr, sum[j], a[j]);
    acc16[idx] = pack8(a);
}

// Bundle SpMM: brep[r] = (1/3)/(deg+1e-8) * Σ acc16[NU+c]   (fp32 out)
__global__ void bi_csr_kernel(const int* __restrict__ off,
                              const int* __restrict__ deg,
                              const int* __restrict__ cv,
                              const uint4* __restrict__ acc16,
                              float* __restrict__ brep) {
    int wave = blockIdx.x * (blockDim.x >> 6) + (threadIdx.x >> 6);
    int sub  = (threadIdx.x >> 3) & 7;
    int l    = threadIdx.x & 7;
    int row  = wave * 8 + sub;
    if (row >= NB_) return;
    int s = off[row], d = deg[row];
    float sum[8] = {0.f, 0.f, 0.f, 0.f, 0.f, 0.f, 0.f, 0.f};
    int k = 0;
    for (; k + 4 <= d; k += 4) {
        int c0 = cv[s + k + 0];
        int c1 = cv[s + k + 1];
        int c2 = cv[s + k + 2];
        int c3 = cv[s + k + 3];
        uint4 x0 = acc16[(size_t)(NU_ + c0) * 8 + l];
        uint4 x1 = acc16[(size_t)(NU_ + c1) * 8 + l];
        uint4 x2 = acc16[(size_t)(NU_ + c2) * 8 + l];
        uint4 x3 = acc16[(size_t)(NU_ + c3) * 8 + l];
        fma8(sum, 1.f, x0);
        fma8(sum, 1.f, x1);
        fma8(sum, 1.f, x2);
        fma8(sum, 1.f, x3);
    }
    for (; k < d; ++k) {
        int c = cv[s + k];
        uint4 x = acc16[(size_t)(NU_ + c) * 8 + l];
        fma8(sum, 1.f, x);
    }
    float scale = (1.0f / 3.0f) / ((float)d + 1e-8f);
    float4 o0, o1;
    o0.x = sum[0] * scale; o0.y = sum[1] * scale;
    o0.z = sum[2] * scale; o0.w = sum[3] * scale;
    o1.x = sum[4] * scale; o1.y = sum[5] * scale;
    o1.z = sum[6] * scale; o1.w = sum[7] * scale;
    float4* bp = (float4*)(brep + (size_t)row * DIM + l * 8);
    bp[0] = o0;
    bp[1] = o1;
}

// ---------------------------------------------------------------------------
__global__ void score_kernel(const unsigned short* __restrict__ acc16u,
                             const float* __restrict__ brep,
                             const int*   __restrict__ users,
                             const int*   __restrict__ bundles,
                             float* __restrict__ loss_sum) {
    int tid  = blockIdx.x * blockDim.x + threadIdx.x;
    int b    = tid >> 6;
    int lane = tid & 63;
    if (b >= BATCH) return;
    int u  = users[b];
    int b0 = bundles[2 * b];
    int b1 = bundles[2 * b + 1];
    float du = __uint_as_float((unsigned int)acc16u[(size_t)u * DIM + lane] << 16)
               * (1.0f / 3.0f);
    float d  = du * (brep[(size_t)b0 * DIM + lane] -
                     brep[(size_t)b1 * DIM + lane]);
    #pragma unroll
    for (int off = 32; off > 0; off >>= 1)
        d += __shfl_down(d, off, 64);
    if (lane == 0) {
        float x = d;
        float l = fmaxf(-x, 0.0f) + log1pf(expf(-fabsf(x)));
        atomicAdd(loss_sum, l);
    }
}

// ---------------------------------------------------------------------------
__global__ void finalize_kernel(const float* __restrict__ loss_sum,
                                float* __restrict__ out) {
    out[0] = loss_sum[0] * (1.0f / BATCH);
    out[1] = 0.0f;
}

// ---------------------------------------------------------------------------
extern "C" void kernel_launch(void* const* d_in, const int* in_sizes, int n_in,
                              void* d_out, int out_size, void* d_ws, size_t ws_size,
                              hipStream_t stream) {
    const float* uf        = (const float*)d_in[0];
    const float* itf       = (const float*)d_in[1];
    const int*   prop_rows = (const int*)  d_in[4];
    const int*   prop_cols = (const int*)  d_in[5];
    const int*   bi_rows   = (const int*)  d_in[6];
    const int*   bi_cols   = (const int*)  d_in[7];
    const int*   users     = (const int*)  d_in[8];
    const int*   bundles   = (const int*)  d_in[9];
    float* out = (float*)d_out;

    char* ws = (char*)d_ws;
    uint4*        acc16   = (uint4*)       (ws + 0);           // 19.2 MB
    uint4*        f1s16   = (uint4*)       (ws + 19200000);    // 19.2 MB
    uint4*        feats16 = (uint4*)       (ws + 38400000);    // 19.2 MB
    float*        brep    = (float*)       (ws + 57600000);    // 5.12 MB
    int*          cvP     = (int*)         (ws + 62720000);    // 16 MB
    unsigned int* binnedP = (unsigned int*)(ws + 78720000);    // 16 MB
    int*          cvB     = (int*)         (ws + 94720000);    // 2.4 MB
    unsigned int* binnedB = (unsigned int*)(ws + 97120000);    // 2.4 MB
    int*          degP    = (int*)         (ws + 99520000);
    int*          offP    = (int*)         (ws + 100120000);
    float*        invsP   = (float*)       (ws + 100720000);
    int*          degB    = (int*)         (ws + 101320000);
    int*          offB    = (int*)         (ws + 101400000);
    int*          binoffP = (int*)         (ws + 101480000);
    int*          gcurP   = (int*)         (ws + 101482368);
    int*          binoffB = (int*)         (ws + 101484736);
    int*          gcurB   = (int*)         (ws + 101485056);
    // contiguous zero-init region: bcntP | bcntB | loss
    int*          bcntP   = (int*)         (ws + 101485376);   // 2368 B
    int*          bcntB   = (int*)         (ws + 101487744);   // 320 B
    float*        loss    = (float*)       (ws + 101488064);   // 4 B

    hipMemsetAsync(bcntP, 0, 2692, stream);   // bcntP + bcntB + loss

    // 1) cast + histograms (fused)
    prep_kernel<<<CAST_BLOCKS + HISTP_BLOCKS + HISTB_BLOCKS, 256, 0, stream>>>(
        (const float4*)uf, (const float4*)itf, (uint2*)feats16,
        prop_rows, bi_rows, bcntP, bcntB);

    // 2) bin-offset scans (P and B in one launch)
    scan_kernel<<<2, 1024, 0, stream>>>(bcntP, binoffP, gcurP,
                                        bcntB, binoffB, gcurB);

    // 3) staged multisplit (P+B fused)
    multisplit_kernel<<<MSP_BLOCKS + MSB_BLOCKS, 256, 0, stream>>>(
        prop_rows, prop_cols, bi_rows, bi_cols,
        gcurP, binnedP, gcurB, binnedB);

    // 4) per-bin CSR build (P+B fused)
    bin_csr_kernel<<<NBIN_P + NBIN_B, 256, 0, stream>>>(
        binnedP, binoffP, offP, degP, invsP, cvP,
        binnedB, binoffB, offB, degB, cvB);

    // 5-7) propagation
    layer1_kernel<<<(NTOT + 31) / 32, 256, 0, stream>>>(offP, degP, cvP, invsP,
                                                        feats16, f1s16, acc16);
    layer2_kernel<<<(NTOT + 31) / 32, 256, 0, stream>>>(offP, degP, cvP, invsP,
                                                        f1s16, acc16);
    bi_csr_kernel<<<(NB_ + 31) / 32, 256, 0, stream>>>(offB, degB, cvB, acc16, brep);

    // 8-9) loss
    score_kernel<<<BATCH * 64 / 256, 256, 0, stream>>>(
        (const unsigned short*)acc16, brep, users, bundles, loss);
    finalize_kernel<<<1, 1, 0, stream>>>(loss, out);
}